// Round 10
// baseline (959.079 us; speedup 1.0000x reference)
//
#include <hip/hip_runtime.h>
#include <hip/hip_bf16.h>
#include <math.h>

// B=32 graphs, N=256 nodes/graph, D=128.
#define DD   128
#define NPG  256
#define NGR  32
#define TTOT 8192
#define LOG2E  1.4426950408889634f
#define LOG2E2 2.8853900817779268f   // 2*log2(e)
#define KSTRIDE 264                   // LDS floats per transposed key row
#define SSTR    268                   // spartS row stride
#define WST     132                   // precompute LDS stride (float4-aligned, 4-bank row spread)
#define H2A(j)  ((j) + (((j)>>5)<<3))   // stagger: chunk base -> bank chunk*8
#define PAD16(j) ((j) + (((j)>>4)<<2))  // eq/v pad

__device__ __forceinline__ float dot4(float4 a, float4 b){
  return a.x*b.x + a.y*b.y + a.z*b.z + a.w*b.w;
}
// ---- DPP cross-lane (VALU pipe) ----
template<int CTRL, int RMASK>
__device__ __forceinline__ float upd_f(float oldv, float x){
  return __int_as_float(__builtin_amdgcn_update_dpp(
      __float_as_int(oldv), __float_as_int(x), CTRL, RMASK, 0xf, false));
}
__device__ __forceinline__ float dpp_wave_sum(float x){
  x += upd_f<0x111,0xf>(0.f, x);   // row_shr:1
  x += upd_f<0x112,0xf>(0.f, x);   // row_shr:2
  x += upd_f<0x114,0xf>(0.f, x);   // row_shr:4
  x += upd_f<0x118,0xf>(0.f, x);   // row_shr:8
  x += upd_f<0x142,0xa>(0.f, x);   // row_bcast15
  x += upd_f<0x143,0xc>(0.f, x);   // row_bcast31
  return __uint_as_float(__builtin_amdgcn_readlane(__float_as_uint(x), 63));
}
__device__ __forceinline__ float dpp_wave_max(float x){
  const float NI = -INFINITY;
  x = fmaxf(x, upd_f<0x111,0xf>(NI, x));
  x = fmaxf(x, upd_f<0x112,0xf>(NI, x));
  x = fmaxf(x, upd_f<0x114,0xf>(NI, x));
  x = fmaxf(x, upd_f<0x118,0xf>(NI, x));
  x = fmaxf(x, upd_f<0x142,0xa>(NI, x));
  x = fmaxf(x, upd_f<0x143,0xc>(NI, x));
  return __uint_as_float(__builtin_amdgcn_readlane(__float_as_uint(x), 63));
}
__device__ __forceinline__ float sigfast(float x){
  return __builtin_amdgcn_rcpf(1.f + __builtin_amdgcn_exp2f(-x*LOG2E));
}
__device__ __forceinline__ float tanhfast(float y){
  return 1.f - 2.f*__builtin_amdgcn_rcpf(1.f + __builtin_amdgcn_exp2f(y*LOG2E2));
}

// ---------------- Kernel 1: parallel precompute ----------------
// keysE[d][n] = exp(2 * l2norm(relu(emb@Wk1.T+bk1)@Wk2.T+bk2)[n][d])  [128][8192] TRANSPOSED
// gi_all = emb@W_ih.T + b_ih                                          [8192,384]
// mm_tile k-loop vectorized: float4 LDS reads (4x fewer ds instructions than
// the scalar version; W-reads are 8-lane-uniform -> broadcast).

__device__ __forceinline__ void load_w128(float* Ws, const float* __restrict__ W, int t){
  const float4* src = (const float4*)W;
  #pragma unroll
  for (int m=0;m<16;m++){
    int idx = m*256+t; int r = idx>>5, c4 = idx&31;
    *(float4*)(&Ws[r*WST + c4*4]) = src[idx];
  }
}

__device__ __forceinline__ void mm_tile(const float* __restrict__ inS, const float* __restrict__ Ws,
                                        float acc[4][4], int jg, int ng){
  #pragma unroll
  for(int r=0;r<4;r++)
    #pragma unroll
    for(int c=0;c<4;c++) acc[r][c]=0.f;
  #pragma unroll 8
  for (int k=0;k<128;k+=4){
    float4 w4[4], x4[4];
    #pragma unroll
    for (int r=0;r<4;r++) w4[r] = *(const float4*)&Ws[(jg*4+r)*WST + k];
    #pragma unroll
    for (int c=0;c<4;c++) x4[c] = *(const float4*)&inS[(ng*4+c)*WST + k];
    #pragma unroll
    for (int r=0;r<4;r++)
      #pragma unroll
      for (int c=0;c<4;c++) acc[r][c] += dot4(w4[r], x4[c]);
  }
}

__global__ __launch_bounds__(256) void precompute_kernel(
    const float* __restrict__ emb,
    const float* __restrict__ Wk1, const float* __restrict__ bk1,
    const float* __restrict__ Wk2, const float* __restrict__ bk2,
    const float* __restrict__ Wih, const float* __restrict__ bih,
    float* __restrict__ keysE, float* __restrict__ giall)
{
  __shared__ __align__(16) float xs[32*WST];
  __shared__ __align__(16) float Ws[128*WST];
  __shared__ __align__(16) float hs[32*WST];
  __shared__ __align__(16) float os[32*WST];
  __shared__ float nrm[32];
  const int t  = threadIdx.x;
  const int n0 = blockIdx.x * 32;
  const int ng = t & 7, jg = t >> 3;

  {
    const float4* src = (const float4*)emb + (size_t)n0*32;
    #pragma unroll
    for (int m=0;m<4;m++){
      int idx = m*256+t; int n = idx>>5, c4 = idx&31;
      *(float4*)(&xs[n*WST + c4*4]) = src[idx];
    }
  }
  load_w128(Ws, Wk1, t);
  __syncthreads();
  {
    float acc[4][4];
    mm_tile(xs, Ws, acc, jg, ng);
    #pragma unroll
    for (int r=0;r<4;r++){
      float bb = bk1[jg*4+r];
      #pragma unroll
      for (int c=0;c<4;c++) hs[(ng*4+c)*WST + jg*4+r] = fmaxf(acc[r][c]+bb, 0.f);
    }
  }
  __syncthreads();
  load_w128(Ws, Wk2, t);
  __syncthreads();
  {
    float acc[4][4];
    mm_tile(hs, Ws, acc, jg, ng);
    #pragma unroll
    for (int r=0;r<4;r++){
      float bb = bk2[jg*4+r];
      #pragma unroll
      for (int c=0;c<4;c++) os[(ng*4+c)*WST + jg*4+r] = acc[r][c]+bb;
    }
  }
  __syncthreads();
  if (t<32){
    float ss=0.f;
    for (int j=0;j<128;j++){ float x = os[t*WST+j]; ss += x*x; }
    nrm[t] = fmaxf(sqrtf(ss), 1e-12f);
  }
  __syncthreads();
  // transposed E-keys: keysE[d][n] = exp(2*K)
  #pragma unroll
  for (int m=0;m<16;m++){
    int idx = m*256+t; int nl = idx & 31, d = idx >> 5;
    float kk = os[nl*WST + d] / nrm[nl];
    keysE[(size_t)d*TTOT + n0 + nl] = __builtin_amdgcn_exp2f(kk * LOG2E2);
  }
  for (int c=0;c<3;c++){
    __syncthreads();
    load_w128(Ws, Wih + c*16384, t);
    __syncthreads();
    float acc[4][4];
    mm_tile(xs, Ws, acc, jg, ng);
    #pragma unroll
    for (int r=0;r<4;r++){
      float bb = bih[c*128 + jg*4+r];
      #pragma unroll
      for (int cc=0;cc<4;cc++)
        giall[(size_t)(n0 + ng*4+cc)*384 + c*128 + jg*4 + r] = acc[r][cc] + bb;
    }
  }
}

// ---------------- Kernel 2: sequential decode ----------------
// 32 blocks x 512 threads; 255 steps; 6 barriers/step.
// Matvec mapping: row = w*16+(L&15), chunk s3 = L>>4 -> each 8-lane LDS phase
// reads ONE uniform h-address (broadcast, conflict-free). 4-chunk reduce via
// shfl_xor(16,32) — same association order as quad-DPP (bit-identical).
// Persistent regs/lane = 160 floats (no-spill point, R3/R6-proven).

__global__ __launch_bounds__(512, 2) void decode_kernel(
    const float* __restrict__ emb,
    const float* __restrict__ keysE, const float* __restrict__ giall,
    const float* __restrict__ Whh, const float* __restrict__ bhh,
    const float* __restrict__ Wq1, const float* __restrict__ bq1,
    const float* __restrict__ Wq2, const float* __restrict__ bq2,
    const float* __restrict__ v,   const float* __restrict__ Wh,
    const float* __restrict__ bh,  const int* __restrict__ start_nodes,
    float* __restrict__ tours_o, float* __restrict__ lp_o)
{
  __shared__ __align__(16) float keys_s[128*KSTRIDE];  // 132 KB, transposed E-keys
  __shared__ __align__(16) float h_s[2][160];          // staggered (H2A)
  __shared__ __align__(16) float qh_s[160];            // staggered (H2A)
  __shared__ __align__(16) float q_s[128];
  __shared__ __align__(16) float eq_s[160];            // PAD16 layout
  __shared__ __align__(16) float v_sp[160];            // PAD16 layout, -2*v
  __shared__ __align__(16) float spartS[8*SSTR];       // score partials (+init scratch)
  __shared__ int col2node_s[256], node2col_s[256];
  __shared__ float redv[8]; __shared__ int redi[8]; __shared__ float red2[8];

  const int t = threadIdx.x;
  const int b = blockIdx.x;
  const int w  = t >> 6, L  = t & 63;
  const int s3 = L >> 4;                // h-chunk: uniform per 16 lanes
  const int rw = (w<<4) | (L & 15);     // matvec output row 0..127
  const int oct = L & 7, dgrp = L >> 3; // score: col-octet, dim-group

  // register weights: Whh rows rw,128+rw,256+rw (chunk s3*32); Wq1/Wq2 row rw
  float4 whh4[3][8], wq14[8], wq24[8];
  {
    const float4* w0  = (const float4*)(Whh + (size_t)(rw      )*128 + s3*32);
    const float4* w1  = (const float4*)(Whh + (size_t)(128 + rw)*128 + s3*32);
    const float4* w2  = (const float4*)(Whh + (size_t)(256 + rw)*128 + s3*32);
    const float4* q1p = (const float4*)(Wq1 + (size_t)rw*128 + s3*32);
    const float4* q2p = (const float4*)(Wq2 + (size_t)rw*128 + s3*32);
    #pragma unroll
    for (int i=0;i<8;i++){
      whh4[0][i]=w0[i]; whh4[1][i]=w1[i]; whh4[2][i]=w2[i];
      wq14[i]=q1p[i];   wq24[i]=q2p[i];
    }
  }
  const float br = bhh[rw], bz = bhh[128+rw], bn = bhh[256+rw];
  const float b1g = bq1[rw], b2g = bq2[rw];

  if (t<128) v_sp[PAD16(t)] = -2.f * v[t];
  if (t<256){ col2node_s[t] = t; node2col_s[t] = t; }
  { // stage transposed E-keys: coalesced per d-row
    #pragma unroll
    for (int m=0;m<16;m++){
      int idx = m*512 + t; int d = idx>>6, q = idx&63;
      *(float4*)(keys_s + d*KSTRIDE + q*4) =
        *(const float4*)(keysE + (size_t)d*TTOT + b*256 + q*4);
    }
  }
  { // graph-context partial sums (4 parts x 64 nodes)
    int d = t & 127, part = t >> 7;
    float a = 0.f;
    const float* base = emb + (size_t)(b*256 + part*64)*128 + d;
    for (int i=0;i<64;i++) a += base[(size_t)i*128];
    spartS[part*128+d] = a;
  }
  int cur = start_nodes[b];
  __syncthreads();
  if (t<128){
    float a = 0.f;
    #pragma unroll
    for (int p=0;p<4;p++) a += spartS[p*128+t];
    q_s[t] = a * (1.f/256.f);          // gctx temp
  }
  __syncthreads();
  if (t<128){ // hidden0 = gctx@Wh.T + bh  (write staggered)
    float a = bh[t];
    const float* wr = Wh + (size_t)t*128;
    for (int k=0;k<128;k++) a += wr[k]*q_s[k];
    h_s[0][H2A(t)] = a;
  }
  { // sv = sum(v)
    float xv = (t<128) ? v[t] : 0.f;
    float tot = dpp_wave_sum(xv);
    if (L==0) red2[w] = tot;
  }
  __syncthreads();
  float sv = 0.f;
  #pragma unroll
  for (int i=0;i<8;i++) sv += red2[i];

  // gi prefetch for step 0
  float gir=0.f, giz=0.f, gin=0.f;
  if (L<16){
    const float* gp = giall + (size_t)cur*384 + rw;
    gir = gp[0]; giz = gp[128]; gin = gp[256];
  }

  for (int step=0; step<255; step++){
    const int par = step & 1;
    const int V   = 255 - step;          // valid count after removing cur
    const int curl = cur - b*256;

    // ---- swap-remove cur's column (data + index maps) ----
    if (t < 128){
      int px = node2col_s[curl];
      keys_s[t*KSTRIDE + px] = keys_s[t*KSTRIDE + V];
    }
    if (t == 0){
      tours_o[b*256+step] = (float)cur;
      int px = node2col_s[curl];
      int ln = col2node_s[V];
      col2node_s[px] = ln;
      node2col_s[ln] = px;
    }

    // ---- phase A: gh dots + fused GRU -> h_s[par^1] ----
    {
      float a0=0.f,a1=0.f,a2=0.f;
      const float4* hc4 = (const float4*)(h_s[par] + s3*40);  // uniform per phase
      #pragma unroll
      for (int i=0;i<8;i++){
        float4 hv = hc4[i];
        a0 += dot4(whh4[0][i], hv);
        a1 += dot4(whh4[1][i], hv);
        a2 += dot4(whh4[2][i], hv);
      }
      a0 += __shfl_xor(a0,16,64); a0 += __shfl_xor(a0,32,64);
      a1 += __shfl_xor(a1,16,64); a1 += __shfl_xor(a1,32,64);
      a2 += __shfl_xor(a2,16,64); a2 += __shfl_xor(a2,32,64);
      if (L<16){
        float r = sigfast(gir + a0 + br);
        float z = sigfast(giz + a1 + bz);
        float n = tanhfast(gin + r*(a2 + bn));
        h_s[par^1][H2A(rw)] = (1.f-z)*n + z*h_s[par][H2A(rw)];
      }
    }
    __syncthreads();                                   // B1

    { // qh = relu(h@Wq1.T + bq1)
      float a=0.f;
      const float4* hc4 = (const float4*)(h_s[par^1] + s3*40);
      #pragma unroll
      for (int i=0;i<8;i++) a += dot4(wq14[i], hc4[i]);
      a += __shfl_xor(a,16,64); a += __shfl_xor(a,32,64);
      if (L<16) qh_s[H2A(rw)] = fmaxf(a + b1g, 0.f);
    }
    __syncthreads();                                   // B2

    { // q_raw = qh@Wq2.T + bq2 ; per-wave sum-of-squares via DPP
      float a=0.f;
      const float4* qc4 = (const float4*)(qh_s + s3*40);
      #pragma unroll
      for (int i=0;i<8;i++) a += dot4(wq24[i], qc4[i]);
      a += __shfl_xor(a,16,64); a += __shfl_xor(a,32,64);
      float qval = a + b2g;
      if (L<16) q_s[rw] = qval;
      float ssp = (L<16) ? qval*qval : 0.f;
      float tot = dpp_wave_sum(ssp);
      if (L==0) red2[w] = tot;
    }
    __syncthreads();                                   // B3

    if (t<128){ // eq_s[d] = exp(2 * q_d / ||q||)
      float ss = 0.f;
      #pragma unroll
      for (int i=0;i<8;i++) ss += red2[i];
      float rn = 1.f / fmaxf(sqrtf(ss), 1e-12f);
      eq_s[PAD16(t)] = __builtin_amdgcn_exp2f(q_s[t] * rn * LOG2E2);
    }
    __syncthreads();                                   // B3b

    // ---- score: wave w -> cols 32w..32w+31 (SKIPPED when 32w >= V) ----
    if (32*w < V){
      const float* kbase = keys_s + dgrp*16*KSTRIDE + 32*w + oct*4;
      const float* ebase = eq_s  + dgrp*20;
      const float* vbase = v_sp  + dgrp*20;
      float4 acc = {0.f,0.f,0.f,0.f};
      #pragma unroll
      for (int jj=0;jj<16;jj++){
        float eqj = ebase[jj];
        float vj  = vbase[jj];
        float4 K = *(const float4*)(kbase + jj*KSTRIDE);
        float r0 = __builtin_amdgcn_rcpf(fmaf(K.x, eqj, 1.f));
        float r1 = __builtin_amdgcn_rcpf(fmaf(K.y, eqj, 1.f));
        float r2 = __builtin_amdgcn_rcpf(fmaf(K.z, eqj, 1.f));
        float r3 = __builtin_amdgcn_rcpf(fmaf(K.w, eqj, 1.f));
        acc.x = fmaf(vj, r0, acc.x);
        acc.y = fmaf(vj, r1, acc.y);
        acc.z = fmaf(vj, r2, acc.z);
        acc.w = fmaf(vj, r3, acc.w);
      }
      *(float4*)(spartS + dgrp*SSTR + 32*w + oct*4) = acc;
    }
    __syncthreads();                                   // Bs1

    // ---- combine + wave-local argmax & softmax stats (waves 0..3) ----
    if (t < 256){
      float val;
      if (t < V){
        float sum = 0.f;
        #pragma unroll
        for (int i=0;i<8;i++) sum += spartS[i*SSTR + t];
        val = sv + sum;
      } else val = -INFINITY;
      float m = dpp_wave_max(val);
      unsigned long long mk = __ballot(val == m);
      int ri = (w<<6) + (__ffsll(mk) - 1);             // column index
      float e = (t < V) ? __builtin_amdgcn_exp2f((val - m)*LOG2E) : 0.f;
      float Sw = dpp_wave_sum(e);
      if (L==0){ redv[w]=m; redi[w]=ri; red2[w]=Sw; }
    }
    __syncthreads();                                   // Bs2

    // ---- tail: redundant global argmax, col->node, gi prefetch, lp ----
    {
      float m = redv[0]; int besti = redi[0];
      #pragma unroll
      for (int i=1;i<4;i++){
        float ov=redv[i]; int oi=redi[i];
        if (ov > m || (ov==m && oi<besti)){ m=ov; besti=oi; }
      }
      cur = b*256 + col2node_s[besti];
      if (L<16){   // prefetch next gi (consumed in next phase A)
        const float* gp = giall + (size_t)cur*384 + rw;
        gir = gp[0]; giz = gp[128]; gin = gp[256];
      }
      if (t==0){
        float sum = 0.f;
        #pragma unroll
        for (int i=0;i<4;i++)
          sum += red2[i] * __builtin_amdgcn_exp2f((redv[i]-m)*LOG2E);
        lp_o[b*255+step] = logf(1.f/sum + 1e-10f);
      }
    }
  }
  if (t==0) tours_o[b*256+255] = (float)cur;
}

extern "C" void kernel_launch(void* const* d_in, const int* in_sizes, int n_in,
                              void* d_out, int out_size, void* d_ws, size_t ws_size,
                              hipStream_t stream) {
  const float* emb  = (const float*)d_in[0];
  const int*   startn = (const int*)d_in[1];
  const float* Wq1 = (const float*)d_in[3];  const float* bq1 = (const float*)d_in[4];
  const float* Wq2 = (const float*)d_in[5];  const float* bq2 = (const float*)d_in[6];
  const float* Wk1 = (const float*)d_in[7];  const float* bk1 = (const float*)d_in[8];
  const float* Wk2 = (const float*)d_in[9];  const float* bk2 = (const float*)d_in[10];
  const float* Wih = (const float*)d_in[11]; const float* Whh = (const float*)d_in[12];
  const float* bih = (const float*)d_in[13]; const float* bhh = (const float*)d_in[14];
  const float* v   = (const float*)d_in[15]; const float* Wh  = (const float*)d_in[16];
  const float* bh  = (const float*)d_in[17];

  float* keysE = (float*)d_ws;               // exp(2*keys) TRANSPOSED [128][8192]
  float* giall = keysE + (size_t)TTOT*DD;    // [8192*384]

  float* outp = (float*)d_out;   // tours [32*256] then log_probs [32*255]

  precompute_kernel<<<256, 256, 0, stream>>>(emb, Wk1, bk1, Wk2, bk2, Wih, bih, keysE, giall);
  decode_kernel<<<NGR, 512, 0, stream>>>(emb, keysE, giall, Whh, bhh, Wq1, bq1, Wq2, bq2,
                                         v, Wh, bh, startn, outp, outp + TTOT);
}

// Round 11
// 913.462 us; speedup vs baseline: 1.0499x; 1.0499x over previous
//
#include <hip/hip_runtime.h>
#include <hip/hip_bf16.h>
#include <math.h>

// B=32 graphs, N=256 nodes/graph, D=128.
#define DD   128
#define NPG  256
#define NGR  32
#define TTOT 8192
#define LOG2E  1.4426950408889634f
#define LOG2E2 2.8853900817779268f   // 2*log2(e)
#define KSTRIDE 264                   // LDS floats per transposed key row
#define SSTR    268                   // spartS row stride
#define WST     132                   // precompute LDS stride (float4-aligned)
#define H2A(j)  ((j) + (((j)>>5)<<3))   // stagger: chunk base -> bank chunk*8
#define PAD16(j) ((j) + (((j)>>4)<<2))  // eq/v pad

__device__ __forceinline__ float dot4(float4 a, float4 b){
  return a.x*b.x + a.y*b.y + a.z*b.z + a.w*b.w;
}
// ---- DPP cross-lane (VALU pipe; keep bpermute OFF the critical chain) ----
template<int CTRL, int RMASK>
__device__ __forceinline__ float upd_f(float oldv, float x){
  return __int_as_float(__builtin_amdgcn_update_dpp(
      __float_as_int(oldv), __float_as_int(x), CTRL, RMASK, 0xf, false));
}
__device__ __forceinline__ float dpp_xor1(float x){
  return __int_as_float(__builtin_amdgcn_mov_dpp(__float_as_int(x), 0xB1, 0xf, 0xf, false));
}
__device__ __forceinline__ float dpp_xor2(float x){
  return __int_as_float(__builtin_amdgcn_mov_dpp(__float_as_int(x), 0x4E, 0xf, 0xf, false));
}
__device__ __forceinline__ float quad_sum_dpp(float x){
  float s = x + dpp_xor1(x);
  return s + dpp_xor2(s);
}
__device__ __forceinline__ float dpp_wave_sum(float x){
  x += upd_f<0x111,0xf>(0.f, x);   // row_shr:1
  x += upd_f<0x112,0xf>(0.f, x);   // row_shr:2
  x += upd_f<0x114,0xf>(0.f, x);   // row_shr:4
  x += upd_f<0x118,0xf>(0.f, x);   // row_shr:8
  x += upd_f<0x142,0xa>(0.f, x);   // row_bcast15
  x += upd_f<0x143,0xc>(0.f, x);   // row_bcast31
  return __uint_as_float(__builtin_amdgcn_readlane(__float_as_uint(x), 63));
}
__device__ __forceinline__ float dpp_wave_max(float x){
  const float NI = -INFINITY;
  x = fmaxf(x, upd_f<0x111,0xf>(NI, x));
  x = fmaxf(x, upd_f<0x112,0xf>(NI, x));
  x = fmaxf(x, upd_f<0x114,0xf>(NI, x));
  x = fmaxf(x, upd_f<0x118,0xf>(NI, x));
  x = fmaxf(x, upd_f<0x142,0xa>(NI, x));
  x = fmaxf(x, upd_f<0x143,0xc>(NI, x));
  return __uint_as_float(__builtin_amdgcn_readlane(__float_as_uint(x), 63));
}
__device__ __forceinline__ float sigfast(float x){
  return __builtin_amdgcn_rcpf(1.f + __builtin_amdgcn_exp2f(-x*LOG2E));
}
__device__ __forceinline__ float tanhfast(float y){
  return 1.f - 2.f*__builtin_amdgcn_rcpf(1.f + __builtin_amdgcn_exp2f(y*LOG2E2));
}

// ---------------- Kernel 1: parallel precompute (R10 vectorized) ----------------
// keysE[d][n] = exp(2 * l2norm(relu(emb@Wk1.T+bk1)@Wk2.T+bk2)[n][d])  [128][8192] TRANSPOSED
// gi_all = emb@W_ih.T + b_ih                                          [8192,384]

__device__ __forceinline__ void load_w128(float* Ws, const float* __restrict__ W, int t){
  const float4* src = (const float4*)W;
  #pragma unroll
  for (int m=0;m<16;m++){
    int idx = m*256+t; int r = idx>>5, c4 = idx&31;
    *(float4*)(&Ws[r*WST + c4*4]) = src[idx];
  }
}

__device__ __forceinline__ void mm_tile(const float* __restrict__ inS, const float* __restrict__ Ws,
                                        float acc[4][4], int jg, int ng){
  #pragma unroll
  for(int r=0;r<4;r++)
    #pragma unroll
    for(int c=0;c<4;c++) acc[r][c]=0.f;
  #pragma unroll 8
  for (int k=0;k<128;k+=4){
    float4 w4[4], x4[4];
    #pragma unroll
    for (int r=0;r<4;r++) w4[r] = *(const float4*)&Ws[(jg*4+r)*WST + k];
    #pragma unroll
    for (int c=0;c<4;c++) x4[c] = *(const float4*)&inS[(ng*4+c)*WST + k];
    #pragma unroll
    for (int r=0;r<4;r++)
      #pragma unroll
      for (int c=0;c<4;c++) acc[r][c] += dot4(w4[r], x4[c]);
  }
}

__global__ __launch_bounds__(256) void precompute_kernel(
    const float* __restrict__ emb,
    const float* __restrict__ Wk1, const float* __restrict__ bk1,
    const float* __restrict__ Wk2, const float* __restrict__ bk2,
    const float* __restrict__ Wih, const float* __restrict__ bih,
    float* __restrict__ keysE, float* __restrict__ giall)
{
  __shared__ __align__(16) float xs[32*WST];
  __shared__ __align__(16) float Ws[128*WST];
  __shared__ __align__(16) float hs[32*WST];
  __shared__ __align__(16) float os[32*WST];
  __shared__ float nrm[32];
  const int t  = threadIdx.x;
  const int n0 = blockIdx.x * 32;
  const int ng = t & 7, jg = t >> 3;

  {
    const float4* src = (const float4*)emb + (size_t)n0*32;
    #pragma unroll
    for (int m=0;m<4;m++){
      int idx = m*256+t; int n = idx>>5, c4 = idx&31;
      *(float4*)(&xs[n*WST + c4*4]) = src[idx];
    }
  }
  load_w128(Ws, Wk1, t);
  __syncthreads();
  {
    float acc[4][4];
    mm_tile(xs, Ws, acc, jg, ng);
    #pragma unroll
    for (int r=0;r<4;r++){
      float bb = bk1[jg*4+r];
      #pragma unroll
      for (int c=0;c<4;c++) hs[(ng*4+c)*WST + jg*4+r] = fmaxf(acc[r][c]+bb, 0.f);
    }
  }
  __syncthreads();
  load_w128(Ws, Wk2, t);
  __syncthreads();
  {
    float acc[4][4];
    mm_tile(hs, Ws, acc, jg, ng);
    #pragma unroll
    for (int r=0;r<4;r++){
      float bb = bk2[jg*4+r];
      #pragma unroll
      for (int c=0;c<4;c++) os[(ng*4+c)*WST + jg*4+r] = acc[r][c]+bb;
    }
  }
  __syncthreads();
  if (t<32){
    float ss=0.f;
    for (int j=0;j<128;j++){ float x = os[t*WST+j]; ss += x*x; }
    nrm[t] = fmaxf(sqrtf(ss), 1e-12f);
  }
  __syncthreads();
  // transposed E-keys: keysE[d][n] = exp(2*K)
  #pragma unroll
  for (int m=0;m<16;m++){
    int idx = m*256+t; int nl = idx & 31, d = idx >> 5;
    float kk = os[nl*WST + d] / nrm[nl];
    keysE[(size_t)d*TTOT + n0 + nl] = __builtin_amdgcn_exp2f(kk * LOG2E2);
  }
  for (int c=0;c<3;c++){
    __syncthreads();
    load_w128(Ws, Wih + c*16384, t);
    __syncthreads();
    float acc[4][4];
    mm_tile(xs, Ws, acc, jg, ng);
    #pragma unroll
    for (int r=0;r<4;r++){
      float bb = bih[c*128 + jg*4+r];
      #pragma unroll
      for (int cc=0;cc<4;cc++)
        giall[(size_t)(n0 + ng*4+cc)*384 + c*128 + jg*4 + r] = acc[r][cc] + bb;
    }
  }
}

// ---------------- Kernel 2: sequential decode (R9 structure + race fix) ----------------
// 32 blocks x 512 threads; 255 steps; 6 barriers/step.
// RACE FIX (R10's absmax=40): the chosen node's column px == besti, so the
// old tail read col2node_s[besti] raced with next-top's col2node_s[px] write
// (no barrier between). Now column->node mapping happens in the combine phase
// (between Bs1 and Bs2) so Bs2 orders it before any map update; the tail
// reads no LDS maps. R10's shfl_xor(16/32) matvec remap reverted: it put 10
// ds_bpermutes back on the critical chain + spilled 4 regs (-60us).

__global__ __launch_bounds__(512, 2) void decode_kernel(
    const float* __restrict__ emb,
    const float* __restrict__ keysE, const float* __restrict__ giall,
    const float* __restrict__ Whh, const float* __restrict__ bhh,
    const float* __restrict__ Wq1, const float* __restrict__ bq1,
    const float* __restrict__ Wq2, const float* __restrict__ bq2,
    const float* __restrict__ v,   const float* __restrict__ Wh,
    const float* __restrict__ bh,  const int* __restrict__ start_nodes,
    float* __restrict__ tours_o, float* __restrict__ lp_o)
{
  __shared__ __align__(16) float keys_s[128*KSTRIDE];  // 132 KB, transposed E-keys
  __shared__ __align__(16) float h_s[2][160];          // staggered (H2A)
  __shared__ __align__(16) float qh_s[160];            // staggered (H2A)
  __shared__ __align__(16) float q_s[128];
  __shared__ __align__(16) float eq_s[160];            // PAD16 layout
  __shared__ __align__(16) float v_sp[160];            // PAD16 layout, -2*v
  __shared__ __align__(16) float spartS[8*SSTR];       // score partials (+init scratch)
  __shared__ int col2node_s[256], node2col_s[256];
  __shared__ float redv[8]; __shared__ int redi[8]; __shared__ float red2[8];

  const int t = threadIdx.x;
  const int b = blockIdx.x;
  const int g  = t >> 2, s3 = t & 3;   // 128 groups x 4 lanes (matvec)
  const int w  = t >> 6, L  = t & 63;
  const int oct = L & 7, dgrp = L >> 3; // score: col-octet, dim-group

  // register weights: Whh rows g,128+g,256+g (chunk s3*32); Wq1/Wq2 row g
  float4 whh4[3][8], wq14[8], wq24[8];
  {
    const float4* w0  = (const float4*)(Whh + (size_t)(g      )*128 + s3*32);
    const float4* w1  = (const float4*)(Whh + (size_t)(128 + g)*128 + s3*32);
    const float4* w2  = (const float4*)(Whh + (size_t)(256 + g)*128 + s3*32);
    const float4* q1p = (const float4*)(Wq1 + (size_t)g*128 + s3*32);
    const float4* q2p = (const float4*)(Wq2 + (size_t)g*128 + s3*32);
    #pragma unroll
    for (int i=0;i<8;i++){
      whh4[0][i]=w0[i]; whh4[1][i]=w1[i]; whh4[2][i]=w2[i];
      wq14[i]=q1p[i];   wq24[i]=q2p[i];
    }
  }
  const float br = bhh[g], bz = bhh[128+g], bn = bhh[256+g];
  const float b1g = bq1[g], b2g = bq2[g];

  if (t<128) v_sp[PAD16(t)] = -2.f * v[t];
  if (t<256){ col2node_s[t] = t; node2col_s[t] = t; }
  { // stage transposed E-keys: coalesced per d-row
    #pragma unroll
    for (int m=0;m<16;m++){
      int idx = m*512 + t; int d = idx>>6, q = idx&63;
      *(float4*)(keys_s + d*KSTRIDE + q*4) =
        *(const float4*)(keysE + (size_t)d*TTOT + b*256 + q*4);
    }
  }
  { // graph-context partial sums (4 parts x 64 nodes)
    int d = t & 127, part = t >> 7;
    float a = 0.f;
    const float* base = emb + (size_t)(b*256 + part*64)*128 + d;
    for (int i=0;i<64;i++) a += base[(size_t)i*128];
    spartS[part*128+d] = a;
  }
  int cur = start_nodes[b];
  __syncthreads();
  if (t<128){
    float a = 0.f;
    #pragma unroll
    for (int p=0;p<4;p++) a += spartS[p*128+t];
    q_s[t] = a * (1.f/256.f);          // gctx temp
  }
  __syncthreads();
  if (t<128){ // hidden0 = gctx@Wh.T + bh  (write staggered)
    float a = bh[t];
    const float* wr = Wh + (size_t)t*128;
    for (int k=0;k<128;k++) a += wr[k]*q_s[k];
    h_s[0][H2A(t)] = a;
  }
  { // sv = sum(v)
    float xv = (t<128) ? v[t] : 0.f;
    float tot = dpp_wave_sum(xv);
    if (L==0) red2[w] = tot;
  }
  __syncthreads();
  float sv = 0.f;
  #pragma unroll
  for (int i=0;i<8;i++) sv += red2[i];

  // gi prefetch for step 0
  float gir=0.f, giz=0.f, gin=0.f;
  if (s3==0){
    const float* gp = giall + (size_t)cur*384 + g;
    gir = gp[0]; giz = gp[128]; gin = gp[256];
  }

  for (int step=0; step<255; step++){
    const int par = step & 1;
    const int V   = 255 - step;          // valid count after removing cur
    const int curl = cur - b*256;

    // ---- swap-remove cur's column (data + index maps) ----
    if (t < 128){
      int px = node2col_s[curl];
      keys_s[t*KSTRIDE + px] = keys_s[t*KSTRIDE + V];
    }
    if (t == 0){
      tours_o[b*256+step] = (float)cur;
      int px = node2col_s[curl];
      int ln = col2node_s[V];
      col2node_s[px] = ln;
      node2col_s[ln] = px;
    }

    // ---- phase A: gh dots + fused GRU -> h_s[par^1] ----
    {
      float a0=0.f,a1=0.f,a2=0.f;
      const float4* hc4 = (const float4*)(h_s[par] + s3*40);
      #pragma unroll
      for (int i=0;i<8;i++){
        float4 hv = hc4[i];
        a0 += dot4(whh4[0][i], hv);
        a1 += dot4(whh4[1][i], hv);
        a2 += dot4(whh4[2][i], hv);
      }
      a0 = quad_sum_dpp(a0);
      a1 = quad_sum_dpp(a1);
      a2 = quad_sum_dpp(a2);
      if (s3==0){
        float r = sigfast(gir + a0 + br);
        float z = sigfast(giz + a1 + bz);
        float n = tanhfast(gin + r*(a2 + bn));
        h_s[par^1][H2A(g)] = (1.f-z)*n + z*h_s[par][H2A(g)];
      }
    }
    __syncthreads();                                   // B1

    { // qh = relu(h@Wq1.T + bq1)
      float a=0.f;
      const float4* hc4 = (const float4*)(h_s[par^1] + s3*40);
      #pragma unroll
      for (int i=0;i<8;i++) a += dot4(wq14[i], hc4[i]);
      a = quad_sum_dpp(a);
      if (s3==0) qh_s[H2A(g)] = fmaxf(a + b1g, 0.f);
    }
    __syncthreads();                                   // B2

    { // q_raw = qh@Wq2.T + bq2 ; per-wave sum-of-squares via DPP
      float a=0.f;
      const float4* qc4 = (const float4*)(qh_s + s3*40);
      #pragma unroll
      for (int i=0;i<8;i++) a += dot4(wq24[i], qc4[i]);
      a = quad_sum_dpp(a);
      float qval = a + b2g;
      if (s3==0) q_s[g] = qval;
      float ssp = (s3==0) ? qval*qval : 0.f;
      float tot = dpp_wave_sum(ssp);
      if (L==0) red2[w] = tot;
    }
    __syncthreads();                                   // B3

    if (t<128){ // eq_s[d] = exp(2 * q_d / ||q||)
      float ss = 0.f;
      #pragma unroll
      for (int i=0;i<8;i++) ss += red2[i];
      float rn = 1.f / fmaxf(sqrtf(ss), 1e-12f);
      eq_s[PAD16(t)] = __builtin_amdgcn_exp2f(q_s[t] * rn * LOG2E2);
    }
    __syncthreads();                                   // B3b

    // ---- score: wave w -> cols 32w..32w+31 (SKIPPED when 32w >= V) ----
    if (32*w < V){
      const float* kbase = keys_s + dgrp*16*KSTRIDE + 32*w + oct*4;
      const float* ebase = eq_s  + dgrp*20;
      const float* vbase = v_sp  + dgrp*20;
      float4 acc = {0.f,0.f,0.f,0.f};
      #pragma unroll
      for (int jj=0;jj<16;jj++){
        float eqj = ebase[jj];
        float vj  = vbase[jj];
        float4 K = *(const float4*)(kbase + jj*KSTRIDE);
        float r0 = __builtin_amdgcn_rcpf(fmaf(K.x, eqj, 1.f));
        float r1 = __builtin_amdgcn_rcpf(fmaf(K.y, eqj, 1.f));
        float r2 = __builtin_amdgcn_rcpf(fmaf(K.z, eqj, 1.f));
        float r3 = __builtin_amdgcn_rcpf(fmaf(K.w, eqj, 1.f));
        acc.x = fmaf(vj, r0, acc.x);
        acc.y = fmaf(vj, r1, acc.y);
        acc.z = fmaf(vj, r2, acc.z);
        acc.w = fmaf(vj, r3, acc.w);
      }
      *(float4*)(spartS + dgrp*SSTR + 32*w + oct*4) = acc;
    }
    __syncthreads();                                   // Bs1

    // ---- combine + wave-local argmax & softmax stats (waves 0..3) ----
    // Column->node map read HERE (before Bs2) so the next step's map update
    // (after all waves pass Bs2) can never race with it.
    if (t < 256){
      float val;
      if (t < V){
        float sum = 0.f;
        #pragma unroll
        for (int i=0;i<8;i++) sum += spartS[i*SSTR + t];
        val = sv + sum;
      } else val = -INFINITY;
      float m = dpp_wave_max(val);
      unsigned long long mk = __ballot(val == m);
      int ri = (w<<6) + (__ffsll(mk) - 1);             // column index
      float e = (t < V) ? __builtin_amdgcn_exp2f((val - m)*LOG2E) : 0.f;
      float Sw = dpp_wave_sum(e);
      if (L==0){ redv[w]=m; redi[w]=col2node_s[ri]; red2[w]=Sw; }
    }
    __syncthreads();                                   // Bs2

    // ---- tail: redundant global argmax (node-valued), gi prefetch, lp ----
    {
      float m = redv[0]; int besti = redi[0];
      #pragma unroll
      for (int i=1;i<4;i++){
        float ov=redv[i]; int oi=redi[i];
        if (ov > m || (ov==m && oi<besti)){ m=ov; besti=oi; }
      }
      cur = b*256 + besti;                // besti is already a node index
      if (s3==0){   // prefetch next gi (consumed in next phase A)
        const float* gp = giall + (size_t)cur*384 + g;
        gir = gp[0]; giz = gp[128]; gin = gp[256];
      }
      if (t==0){
        float sum = 0.f;
        #pragma unroll
        for (int i=0;i<4;i++)
          sum += red2[i] * __builtin_amdgcn_exp2f((redv[i]-m)*LOG2E);
        lp_o[b*255+step] = logf(1.f/sum + 1e-10f);
      }
    }
  }
  if (t==0) tours_o[b*256+255] = (float)cur;
}

extern "C" void kernel_launch(void* const* d_in, const int* in_sizes, int n_in,
                              void* d_out, int out_size, void* d_ws, size_t ws_size,
                              hipStream_t stream) {
  const float* emb  = (const float*)d_in[0];
  const int*   startn = (const int*)d_in[1];
  const float* Wq1 = (const float*)d_in[3];  const float* bq1 = (const float*)d_in[4];
  const float* Wq2 = (const float*)d_in[5];  const float* bq2 = (const float*)d_in[6];
  const float* Wk1 = (const float*)d_in[7];  const float* bk1 = (const float*)d_in[8];
  const float* Wk2 = (const float*)d_in[9];  const float* bk2 = (const float*)d_in[10];
  const float* Wih = (const float*)d_in[11]; const float* Whh = (const float*)d_in[12];
  const float* bih = (const float*)d_in[13]; const float* bhh = (const float*)d_in[14];
  const float* v   = (const float*)d_in[15]; const float* Wh  = (const float*)d_in[16];
  const float* bh  = (const float*)d_in[17];

  float* keysE = (float*)d_ws;               // exp(2*keys) TRANSPOSED [128][8192]
  float* giall = keysE + (size_t)TTOT*DD;    // [8192*384]

  float* outp = (float*)d_out;   // tours [32*256] then log_probs [32*255]

  precompute_kernel<<<256, 256, 0, stream>>>(emb, Wk1, bk1, Wk2, bk2, Wih, bih, keysE, giall);
  decode_kernel<<<NGR, 512, 0, stream>>>(emb, keysE, giall, Whh, bhh, Wq1, bq1, Wq2, bq2,
                                         v, Wh, bh, startn, outp, outp + TTOT);
}

// Round 12
// 893.693 us; speedup vs baseline: 1.0732x; 1.0221x over previous
//
#include <hip/hip_runtime.h>
#include <hip/hip_bf16.h>
#include <math.h>

// B=32 graphs, N=256 nodes/graph, D=128.
#define DD   128
#define NPG  256
#define NGR  32
#define TTOT 8192
#define LOG2E  1.4426950408889634f
#define LOG2E2 2.8853900817779268f   // 2*log2(e)
#define KSTRIDE 264                   // LDS floats per transposed key row
#define SSTR    268                   // spartS row stride
#define H2A(j)  ((j) + (((j)>>5)<<3))   // stagger: chunk base -> bank chunk*8
#define PAD16(j) ((j) + (((j)>>4)<<2))  // eq/v pad

__device__ __forceinline__ float dot4(float4 a, float4 b){
  return a.x*b.x + a.y*b.y + a.z*b.z + a.w*b.w;
}
// ---- DPP cross-lane (VALU pipe; keeps ds_bpermute off critical chains) ----
template<int CTRL, int RMASK>
__device__ __forceinline__ float upd_f(float oldv, float x){
  return __int_as_float(__builtin_amdgcn_update_dpp(
      __float_as_int(oldv), __float_as_int(x), CTRL, RMASK, 0xf, false));
}
__device__ __forceinline__ float dpp_xor1(float x){
  return __int_as_float(__builtin_amdgcn_mov_dpp(__float_as_int(x), 0xB1, 0xf, 0xf, false));
}
__device__ __forceinline__ float dpp_xor2(float x){
  return __int_as_float(__builtin_amdgcn_mov_dpp(__float_as_int(x), 0x4E, 0xf, 0xf, false));
}
__device__ __forceinline__ float quad_sum_dpp(float x){
  float s = x + dpp_xor1(x);
  return s + dpp_xor2(s);
}
__device__ __forceinline__ float dpp_wave_sum(float x){
  x += upd_f<0x111,0xf>(0.f, x);   // row_shr:1
  x += upd_f<0x112,0xf>(0.f, x);   // row_shr:2
  x += upd_f<0x114,0xf>(0.f, x);   // row_shr:4
  x += upd_f<0x118,0xf>(0.f, x);   // row_shr:8
  x += upd_f<0x142,0xa>(0.f, x);   // row_bcast15
  x += upd_f<0x143,0xc>(0.f, x);   // row_bcast31
  return __uint_as_float(__builtin_amdgcn_readlane(__float_as_uint(x), 63));
}
__device__ __forceinline__ float dpp_wave_max(float x){
  const float NI = -INFINITY;
  x = fmaxf(x, upd_f<0x111,0xf>(NI, x));
  x = fmaxf(x, upd_f<0x112,0xf>(NI, x));
  x = fmaxf(x, upd_f<0x114,0xf>(NI, x));
  x = fmaxf(x, upd_f<0x118,0xf>(NI, x));
  x = fmaxf(x, upd_f<0x142,0xa>(NI, x));
  x = fmaxf(x, upd_f<0x143,0xc>(NI, x));
  return __uint_as_float(__builtin_amdgcn_readlane(__float_as_uint(x), 63));
}
__device__ __forceinline__ float sigfast(float x){
  return __builtin_amdgcn_rcpf(1.f + __builtin_amdgcn_exp2f(-x*LOG2E));
}
__device__ __forceinline__ float tanhfast(float y){
  return 1.f - 2.f*__builtin_amdgcn_rcpf(1.f + __builtin_amdgcn_exp2f(y*LOG2E2));
}

// ---------------- Kernel 1: parallel precompute (R9 SCALAR version) ----------------
// NOTE: the R10 float4-vectorized mm_tile changed fp accumulation order ->
// 1-ulp keysE shifts -> a near-tie argmax flipped -> tour divergence
// (absmax 40, deterministic). Scalar order is the validated numerics; the
// vectorization bought no measurable time (gap is launch overhead). KEEP SCALAR.
// keysE[d][n] = exp(2 * l2norm(relu(emb@Wk1.T+bk1)@Wk2.T+bk2)[n][d])  [128][8192] TRANSPOSED
// gi_all = emb@W_ih.T + b_ih                                          [8192,384]

__device__ __forceinline__ void load_w128(float* Ws, const float* __restrict__ W, int t){
  const float4* src = (const float4*)W;
  #pragma unroll
  for (int m=0;m<16;m++){
    int idx = m*256+t; int r = idx>>5, c4 = idx&31;
    float4 val = src[idx];
    float* dst = &Ws[r*129 + c4*4];
    dst[0]=val.x; dst[1]=val.y; dst[2]=val.z; dst[3]=val.w;
  }
}

__device__ __forceinline__ void mm_tile(const float* __restrict__ inS, const float* __restrict__ Ws,
                                        float acc[4][4], int jg, int ng){
  #pragma unroll
  for(int r=0;r<4;r++)
    #pragma unroll
    for(int c=0;c<4;c++) acc[r][c]=0.f;
  #pragma unroll 4
  for (int k=0;k<128;k++){
    float w[4], x[4];
    #pragma unroll
    for (int r=0;r<4;r++) w[r] = Ws[(jg*4+r)*129+k];
    #pragma unroll
    for (int c=0;c<4;c++) x[c] = inS[(ng*4+c)*129+k];
    #pragma unroll
    for (int r=0;r<4;r++)
      #pragma unroll
      for (int c=0;c<4;c++) acc[r][c] += w[r]*x[c];
  }
}

__global__ __launch_bounds__(256) void precompute_kernel(
    const float* __restrict__ emb,
    const float* __restrict__ Wk1, const float* __restrict__ bk1,
    const float* __restrict__ Wk2, const float* __restrict__ bk2,
    const float* __restrict__ Wih, const float* __restrict__ bih,
    float* __restrict__ keysE, float* __restrict__ giall)
{
  __shared__ __align__(16) float xs[32*129];
  __shared__ __align__(16) float Ws[128*129];
  __shared__ __align__(16) float hs[32*129];
  __shared__ __align__(16) float os[32*129];
  __shared__ float nrm[32];
  const int t  = threadIdx.x;
  const int n0 = blockIdx.x * 32;
  const int ng = t & 7, jg = t >> 3;

  {
    const float4* src = (const float4*)emb + (size_t)n0*32;
    #pragma unroll
    for (int m=0;m<4;m++){
      int idx = m*256+t; int n = idx>>5, c4 = idx&31;
      float4 val = src[idx];
      float* dst = &xs[n*129 + c4*4];
      dst[0]=val.x; dst[1]=val.y; dst[2]=val.z; dst[3]=val.w;
    }
  }
  load_w128(Ws, Wk1, t);
  __syncthreads();
  {
    float acc[4][4];
    mm_tile(xs, Ws, acc, jg, ng);
    #pragma unroll
    for (int r=0;r<4;r++){
      float bb = bk1[jg*4+r];
      #pragma unroll
      for (int c=0;c<4;c++) hs[(ng*4+c)*129 + jg*4+r] = fmaxf(acc[r][c]+bb, 0.f);
    }
  }
  __syncthreads();
  load_w128(Ws, Wk2, t);
  __syncthreads();
  {
    float acc[4][4];
    mm_tile(hs, Ws, acc, jg, ng);
    #pragma unroll
    for (int r=0;r<4;r++){
      float bb = bk2[jg*4+r];
      #pragma unroll
      for (int c=0;c<4;c++) os[(ng*4+c)*129 + jg*4+r] = acc[r][c]+bb;
    }
  }
  __syncthreads();
  if (t<32){
    float ss=0.f;
    for (int j=0;j<128;j++){ float x = os[t*129+j]; ss += x*x; }
    nrm[t] = fmaxf(sqrtf(ss), 1e-12f);
  }
  __syncthreads();
  // transposed E-keys: keysE[d][n] = exp(2*K)
  #pragma unroll
  for (int m=0;m<16;m++){
    int idx = m*256+t; int nl = idx & 31, d = idx >> 5;
    float kk = os[nl*129 + d] / nrm[nl];
    keysE[(size_t)d*TTOT + n0 + nl] = __builtin_amdgcn_exp2f(kk * LOG2E2);
  }
  for (int c=0;c<3;c++){
    __syncthreads();
    load_w128(Ws, Wih + c*16384, t);
    __syncthreads();
    float acc[4][4];
    mm_tile(xs, Ws, acc, jg, ng);
    #pragma unroll
    for (int r=0;r<4;r++){
      float bb = bih[c*128 + jg*4+r];
      #pragma unroll
      for (int cc=0;cc<4;cc++)
        giall[(size_t)(n0 + ng*4+cc)*384 + c*128 + jg*4 + r] = acc[r][cc] + bb;
    }
  }
}

// ---------------- Kernel 2: sequential decode (R9 structure + zero-cost race fix) --------
// 32 blocks x 512 threads; 255 steps; 6 barriers/step.
// RACE FIX: the t==0 col2node/node2col update moved from loop-top to AFTER B1.
// Tail(s) reads col2node_s[besti]; the conflicting write (same entry, since
// px==besti by construction) now happens after B1(s+1), which all tail(s)
// reads precede. Keys-swap at top still reads the pre-update map (correct).
// No extra LDS ops on any critical chain (R11's combine-phase map read
// caused spill + 12us; reverted).

__global__ __launch_bounds__(512, 2) void decode_kernel(
    const float* __restrict__ emb,
    const float* __restrict__ keysE, const float* __restrict__ giall,
    const float* __restrict__ Whh, const float* __restrict__ bhh,
    const float* __restrict__ Wq1, const float* __restrict__ bq1,
    const float* __restrict__ Wq2, const float* __restrict__ bq2,
    const float* __restrict__ v,   const float* __restrict__ Wh,
    const float* __restrict__ bh,  const int* __restrict__ start_nodes,
    float* __restrict__ tours_o, float* __restrict__ lp_o)
{
  __shared__ __align__(16) float keys_s[128*KSTRIDE];  // 132 KB, transposed E-keys
  __shared__ __align__(16) float h_s[2][160];          // staggered (H2A)
  __shared__ __align__(16) float qh_s[160];            // staggered (H2A)
  __shared__ __align__(16) float q_s[128];
  __shared__ __align__(16) float eq_s[160];            // PAD16 layout
  __shared__ __align__(16) float v_sp[160];            // PAD16 layout, -2*v
  __shared__ __align__(16) float spartS[8*SSTR];       // score partials (+init scratch)
  __shared__ int col2node_s[256], node2col_s[256];
  __shared__ float redv[8]; __shared__ int redi[8]; __shared__ float red2[8];

  const int t = threadIdx.x;
  const int b = blockIdx.x;
  const int g  = t >> 2, s3 = t & 3;   // 128 groups x 4 lanes (matvec)
  const int w  = t >> 6, L  = t & 63;
  const int oct = L & 7, dgrp = L >> 3; // score: col-octet, dim-group

  // register weights: Whh rows g,128+g,256+g (chunk s3*32); Wq1/Wq2 row g
  float4 whh4[3][8], wq14[8], wq24[8];
  {
    const float4* w0  = (const float4*)(Whh + (size_t)(g      )*128 + s3*32);
    const float4* w1  = (const float4*)(Whh + (size_t)(128 + g)*128 + s3*32);
    const float4* w2  = (const float4*)(Whh + (size_t)(256 + g)*128 + s3*32);
    const float4* q1p = (const float4*)(Wq1 + (size_t)g*128 + s3*32);
    const float4* q2p = (const float4*)(Wq2 + (size_t)g*128 + s3*32);
    #pragma unroll
    for (int i=0;i<8;i++){
      whh4[0][i]=w0[i]; whh4[1][i]=w1[i]; whh4[2][i]=w2[i];
      wq14[i]=q1p[i];   wq24[i]=q2p[i];
    }
  }
  const float br = bhh[g], bz = bhh[128+g], bn = bhh[256+g];
  const float b1g = bq1[g], b2g = bq2[g];

  if (t<128) v_sp[PAD16(t)] = -2.f * v[t];
  if (t<256){ col2node_s[t] = t; node2col_s[t] = t; }
  { // stage transposed E-keys: coalesced per d-row
    #pragma unroll
    for (int m=0;m<16;m++){
      int idx = m*512 + t; int d = idx>>6, q = idx&63;
      *(float4*)(keys_s + d*KSTRIDE + q*4) =
        *(const float4*)(keysE + (size_t)d*TTOT + b*256 + q*4);
    }
  }
  { // graph-context partial sums (4 parts x 64 nodes)
    int d = t & 127, part = t >> 7;
    float a = 0.f;
    const float* base = emb + (size_t)(b*256 + part*64)*128 + d;
    for (int i=0;i<64;i++) a += base[(size_t)i*128];
    spartS[part*128+d] = a;
  }
  int cur = start_nodes[b];
  __syncthreads();
  if (t<128){
    float a = 0.f;
    #pragma unroll
    for (int p=0;p<4;p++) a += spartS[p*128+t];
    q_s[t] = a * (1.f/256.f);          // gctx temp
  }
  __syncthreads();
  if (t<128){ // hidden0 = gctx@Wh.T + bh  (write staggered)
    float a = bh[t];
    const float* wr = Wh + (size_t)t*128;
    for (int k=0;k<128;k++) a += wr[k]*q_s[k];
    h_s[0][H2A(t)] = a;
  }
  { // sv = sum(v)
    float xv = (t<128) ? v[t] : 0.f;
    float tot = dpp_wave_sum(xv);
    if (L==0) red2[w] = tot;
  }
  __syncthreads();
  float sv = 0.f;
  #pragma unroll
  for (int i=0;i<8;i++) sv += red2[i];

  // gi prefetch for step 0
  float gir=0.f, giz=0.f, gin=0.f;
  if (s3==0){
    const float* gp = giall + (size_t)cur*384 + g;
    gir = gp[0]; giz = gp[128]; gin = gp[256];
  }

  for (int step=0; step<255; step++){
    const int par = step & 1;
    const int V   = 255 - step;          // valid count after removing cur
    const int curl = cur - b*256;

    // ---- swap-remove cur's keys column (reads PRE-update map; map update
    //      itself deferred to after B1 for the race fix) ----
    if (t < 128){
      int px = node2col_s[curl];
      keys_s[t*KSTRIDE + px] = keys_s[t*KSTRIDE + V];
    }
    if (t == 0) tours_o[b*256+step] = (float)cur;

    // ---- phase A: gh dots + fused GRU -> h_s[par^1] ----
    {
      float a0=0.f,a1=0.f,a2=0.f;
      const float4* hc4 = (const float4*)(h_s[par] + s3*40);
      #pragma unroll
      for (int i=0;i<8;i++){
        float4 hv = hc4[i];
        a0 += dot4(whh4[0][i], hv);
        a1 += dot4(whh4[1][i], hv);
        a2 += dot4(whh4[2][i], hv);
      }
      a0 = quad_sum_dpp(a0);
      a1 = quad_sum_dpp(a1);
      a2 = quad_sum_dpp(a2);
      if (s3==0){
        float r = sigfast(gir + a0 + br);
        float z = sigfast(giz + a1 + bz);
        float n = tanhfast(gin + r*(a2 + bn));
        h_s[par^1][H2A(g)] = (1.f-z)*n + z*h_s[par][H2A(g)];
      }
    }
    __syncthreads();                                   // B1

    // ---- deferred index-map update (race-free: all prev-step tail reads
    //      of col2node_s completed before B1) ----
    if (t == 0){
      int px = node2col_s[curl];
      int ln = col2node_s[V];
      col2node_s[px] = ln;
      node2col_s[ln] = px;
    }

    { // qh = relu(h@Wq1.T + bq1)
      float a=0.f;
      const float4* hc4 = (const float4*)(h_s[par^1] + s3*40);
      #pragma unroll
      for (int i=0;i<8;i++) a += dot4(wq14[i], hc4[i]);
      a = quad_sum_dpp(a);
      if (s3==0) qh_s[H2A(g)] = fmaxf(a + b1g, 0.f);
    }
    __syncthreads();                                   // B2

    { // q_raw = qh@Wq2.T + bq2 ; per-wave sum-of-squares via DPP
      float a=0.f;
      const float4* qc4 = (const float4*)(qh_s + s3*40);
      #pragma unroll
      for (int i=0;i<8;i++) a += dot4(wq24[i], qc4[i]);
      a = quad_sum_dpp(a);
      float qval = a + b2g;
      if (s3==0) q_s[g] = qval;
      float ssp = (s3==0) ? qval*qval : 0.f;
      float tot = dpp_wave_sum(ssp);
      if (L==0) red2[w] = tot;
    }
    __syncthreads();                                   // B3

    if (t<128){ // eq_s[d] = exp(2 * q_d / ||q||)
      float ss = 0.f;
      #pragma unroll
      for (int i=0;i<8;i++) ss += red2[i];
      float rn = 1.f / fmaxf(sqrtf(ss), 1e-12f);
      eq_s[PAD16(t)] = __builtin_amdgcn_exp2f(q_s[t] * rn * LOG2E2);
    }
    __syncthreads();                                   // B3b

    // ---- score: wave w -> cols 32w..32w+31 (SKIPPED when 32w >= V) ----
    if (32*w < V){
      const float* kbase = keys_s + dgrp*16*KSTRIDE + 32*w + oct*4;
      const float* ebase = eq_s  + dgrp*20;
      const float* vbase = v_sp  + dgrp*20;
      float4 acc = {0.f,0.f,0.f,0.f};
      #pragma unroll
      for (int jj=0;jj<16;jj++){
        float eqj = ebase[jj];
        float vj  = vbase[jj];
        float4 K = *(const float4*)(kbase + jj*KSTRIDE);
        float r0 = __builtin_amdgcn_rcpf(fmaf(K.x, eqj, 1.f));
        float r1 = __builtin_amdgcn_rcpf(fmaf(K.y, eqj, 1.f));
        float r2 = __builtin_amdgcn_rcpf(fmaf(K.z, eqj, 1.f));
        float r3 = __builtin_amdgcn_rcpf(fmaf(K.w, eqj, 1.f));
        acc.x = fmaf(vj, r0, acc.x);
        acc.y = fmaf(vj, r1, acc.y);
        acc.z = fmaf(vj, r2, acc.z);
        acc.w = fmaf(vj, r3, acc.w);
      }
      *(float4*)(spartS + dgrp*SSTR + 32*w + oct*4) = acc;
    }
    __syncthreads();                                   // Bs1

    // ---- combine + wave-local argmax & softmax stats (waves 0..3) ----
    if (t < 256){
      float val;
      if (t < V){
        float sum = 0.f;
        #pragma unroll
        for (int i=0;i<8;i++) sum += spartS[i*SSTR + t];
        val = sv + sum;
      } else val = -INFINITY;
      float m = dpp_wave_max(val);
      unsigned long long mk = __ballot(val == m);
      int ri = (w<<6) + (__ffsll(mk) - 1);             // column index
      float e = (t < V) ? __builtin_amdgcn_exp2f((val - m)*LOG2E) : 0.f;
      float Sw = dpp_wave_sum(e);
      if (L==0){ redv[w]=m; redi[w]=ri; red2[w]=Sw; }
    }
    __syncthreads();                                   // Bs2

    // ---- tail: redundant global argmax, col->node, gi prefetch, lp ----
    {
      float m = redv[0]; int besti = redi[0];
      #pragma unroll
      for (int i=1;i<4;i++){
        float ov=redv[i]; int oi=redi[i];
        if (ov > m || (ov==m && oi<besti)){ m=ov; besti=oi; }
      }
      cur = b*256 + col2node_s[besti];
      if (s3==0){   // prefetch next gi (consumed in next phase A)
        const float* gp = giall + (size_t)cur*384 + g;
        gir = gp[0]; giz = gp[128]; gin = gp[256];
      }
      if (t==0){
        float sum = 0.f;
        #pragma unroll
        for (int i=0;i<4;i++)
          sum += red2[i] * __builtin_amdgcn_exp2f((redv[i]-m)*LOG2E);
        lp_o[b*255+step] = logf(1.f/sum + 1e-10f);
      }
    }
  }
  if (t==0) tours_o[b*256+255] = (float)cur;
}

extern "C" void kernel_launch(void* const* d_in, const int* in_sizes, int n_in,
                              void* d_out, int out_size, void* d_ws, size_t ws_size,
                              hipStream_t stream) {
  const float* emb  = (const float*)d_in[0];
  const int*   startn = (const int*)d_in[1];
  const float* Wq1 = (const float*)d_in[3];  const float* bq1 = (const float*)d_in[4];
  const float* Wq2 = (const float*)d_in[5];  const float* bq2 = (const float*)d_in[6];
  const float* Wk1 = (const float*)d_in[7];  const float* bk1 = (const float*)d_in[8];
  const float* Wk2 = (const float*)d_in[9];  const float* bk2 = (const float*)d_in[10];
  const float* Wih = (const float*)d_in[11]; const float* Whh = (const float*)d_in[12];
  const float* bih = (const float*)d_in[13]; const float* bhh = (const float*)d_in[14];
  const float* v   = (const float*)d_in[15]; const float* Wh  = (const float*)d_in[16];
  const float* bh  = (const float*)d_in[17];

  float* keysE = (float*)d_ws;               // exp(2*keys) TRANSPOSED [128][8192]
  float* giall = keysE + (size_t)TTOT*DD;    // [8192*384]

  float* outp = (float*)d_out;   // tours [32*256] then log_probs [32*255]

  precompute_kernel<<<256, 256, 0, stream>>>(emb, Wk1, bk1, Wk2, bk2, Wih, bih, keysE, giall);
  decode_kernel<<<NGR, 512, 0, stream>>>(emb, keysE, giall, Whh, bhh, Wq1, bq1, Wq2, bq2,
                                         v, Wh, bh, startn, outp, outp + TTOT);
}

// Round 13
// 886.431 us; speedup vs baseline: 1.0820x; 1.0082x over previous
//
#include <hip/hip_runtime.h>
#include <hip/hip_bf16.h>
#include <math.h>

// B=32 graphs, N=256 nodes/graph, D=128.
#define DD   128
#define NPG  256
#define NGR  32
#define TTOT 8192
#define LOG2E  1.4426950408889634f
#define LOG2E2 2.8853900817779268f   // 2*log2(e)
#define KSTRIDE 264                   // LDS floats per transposed key row
#define SSTR    268                   // spartS row stride
#define H2A(j)  ((j) + (((j)>>5)<<3))   // stagger: chunk base -> bank chunk*8
#define PAD16(j) ((j) + (((j)>>4)<<2))  // q/v pad: d -> d + (d>>4)*4

__device__ __forceinline__ float dot4(float4 a, float4 b){
  return a.x*b.x + a.y*b.y + a.z*b.z + a.w*b.w;
}
// ---- DPP cross-lane (VALU pipe; keeps ds_bpermute off critical chains) ----
template<int CTRL, int RMASK>
__device__ __forceinline__ float upd_f(float oldv, float x){
  return __int_as_float(__builtin_amdgcn_update_dpp(
      __float_as_int(oldv), __float_as_int(x), CTRL, RMASK, 0xf, false));
}
__device__ __forceinline__ float dpp_xor1(float x){
  return __int_as_float(__builtin_amdgcn_mov_dpp(__float_as_int(x), 0xB1, 0xf, 0xf, false));
}
__device__ __forceinline__ float dpp_xor2(float x){
  return __int_as_float(__builtin_amdgcn_mov_dpp(__float_as_int(x), 0x4E, 0xf, 0xf, false));
}
__device__ __forceinline__ float quad_sum_dpp(float x){
  float s = x + dpp_xor1(x);
  return s + dpp_xor2(s);
}
__device__ __forceinline__ float dpp_wave_sum(float x){
  x += upd_f<0x111,0xf>(0.f, x);   // row_shr:1
  x += upd_f<0x112,0xf>(0.f, x);   // row_shr:2
  x += upd_f<0x114,0xf>(0.f, x);   // row_shr:4
  x += upd_f<0x118,0xf>(0.f, x);   // row_shr:8
  x += upd_f<0x142,0xa>(0.f, x);   // row_bcast15
  x += upd_f<0x143,0xc>(0.f, x);   // row_bcast31
  return __uint_as_float(__builtin_amdgcn_readlane(__float_as_uint(x), 63));
}
__device__ __forceinline__ float dpp_wave_max(float x){
  const float NI = -INFINITY;
  x = fmaxf(x, upd_f<0x111,0xf>(NI, x));
  x = fmaxf(x, upd_f<0x112,0xf>(NI, x));
  x = fmaxf(x, upd_f<0x114,0xf>(NI, x));
  x = fmaxf(x, upd_f<0x118,0xf>(NI, x));
  x = fmaxf(x, upd_f<0x142,0xa>(NI, x));
  x = fmaxf(x, upd_f<0x143,0xc>(NI, x));
  return __uint_as_float(__builtin_amdgcn_readlane(__float_as_uint(x), 63));
}
__device__ __forceinline__ float sigfast(float x){
  return __builtin_amdgcn_rcpf(1.f + __builtin_amdgcn_exp2f(-x*LOG2E));
}
__device__ __forceinline__ float tanhfast(float y){
  return 1.f - 2.f*__builtin_amdgcn_rcpf(1.f + __builtin_amdgcn_exp2f(y*LOG2E2));
}

// ---------------- Kernel 1: parallel precompute (R9/R12 SCALAR version) ----------------
// SCALAR mm_tile accumulation order is part of the validated-numerics contract
// (R10's float4 reorder flipped a near-tie argmax -> tour divergence). DO NOT vectorize.
// keysE[d][n] = exp(2 * l2norm(relu(emb@Wk1.T+bk1)@Wk2.T+bk2)[n][d])  [128][8192] TRANSPOSED
// gi_all = emb@W_ih.T + b_ih                                          [8192,384]

__device__ __forceinline__ void load_w128(float* Ws, const float* __restrict__ W, int t){
  const float4* src = (const float4*)W;
  #pragma unroll
  for (int m=0;m<16;m++){
    int idx = m*256+t; int r = idx>>5, c4 = idx&31;
    float4 val = src[idx];
    float* dst = &Ws[r*129 + c4*4];
    dst[0]=val.x; dst[1]=val.y; dst[2]=val.z; dst[3]=val.w;
  }
}

__device__ __forceinline__ void mm_tile(const float* __restrict__ inS, const float* __restrict__ Ws,
                                        float acc[4][4], int jg, int ng){
  #pragma unroll
  for(int r=0;r<4;r++)
    #pragma unroll
    for(int c=0;c<4;c++) acc[r][c]=0.f;
  #pragma unroll 4
  for (int k=0;k<128;k++){
    float w[4], x[4];
    #pragma unroll
    for (int r=0;r<4;r++) w[r] = Ws[(jg*4+r)*129+k];
    #pragma unroll
    for (int c=0;c<4;c++) x[c] = inS[(ng*4+c)*129+k];
    #pragma unroll
    for (int r=0;r<4;r++)
      #pragma unroll
      for (int c=0;c<4;c++) acc[r][c] += w[r]*x[c];
  }
}

__global__ __launch_bounds__(256) void precompute_kernel(
    const float* __restrict__ emb,
    const float* __restrict__ Wk1, const float* __restrict__ bk1,
    const float* __restrict__ Wk2, const float* __restrict__ bk2,
    const float* __restrict__ Wih, const float* __restrict__ bih,
    float* __restrict__ keysE, float* __restrict__ giall)
{
  __shared__ __align__(16) float xs[32*129];
  __shared__ __align__(16) float Ws[128*129];
  __shared__ __align__(16) float hs[32*129];
  __shared__ __align__(16) float os[32*129];
  __shared__ float nrm[32];
  const int t  = threadIdx.x;
  const int n0 = blockIdx.x * 32;
  const int ng = t & 7, jg = t >> 3;

  {
    const float4* src = (const float4*)emb + (size_t)n0*32;
    #pragma unroll
    for (int m=0;m<4;m++){
      int idx = m*256+t; int n = idx>>5, c4 = idx&31;
      float4 val = src[idx];
      float* dst = &xs[n*129 + c4*4];
      dst[0]=val.x; dst[1]=val.y; dst[2]=val.z; dst[3]=val.w;
    }
  }
  load_w128(Ws, Wk1, t);
  __syncthreads();
  {
    float acc[4][4];
    mm_tile(xs, Ws, acc, jg, ng);
    #pragma unroll
    for (int r=0;r<4;r++){
      float bb = bk1[jg*4+r];
      #pragma unroll
      for (int c=0;c<4;c++) hs[(ng*4+c)*129 + jg*4+r] = fmaxf(acc[r][c]+bb, 0.f);
    }
  }
  __syncthreads();
  load_w128(Ws, Wk2, t);
  __syncthreads();
  {
    float acc[4][4];
    mm_tile(hs, Ws, acc, jg, ng);
    #pragma unroll
    for (int r=0;r<4;r++){
      float bb = bk2[jg*4+r];
      #pragma unroll
      for (int c=0;c<4;c++) os[(ng*4+c)*129 + jg*4+r] = acc[r][c]+bb;
    }
  }
  __syncthreads();
  if (t<32){
    float ss=0.f;
    for (int j=0;j<128;j++){ float x = os[t*129+j]; ss += x*x; }
    nrm[t] = fmaxf(sqrtf(ss), 1e-12f);
  }
  __syncthreads();
  // transposed E-keys: keysE[d][n] = exp(2*K)
  #pragma unroll
  for (int m=0;m<16;m++){
    int idx = m*256+t; int nl = idx & 31, d = idx >> 5;
    float kk = os[nl*129 + d] / nrm[nl];
    keysE[(size_t)d*TTOT + n0 + nl] = __builtin_amdgcn_exp2f(kk * LOG2E2);
  }
  for (int c=0;c<3;c++){
    __syncthreads();
    load_w128(Ws, Wih + c*16384, t);
    __syncthreads();
    float acc[4][4];
    mm_tile(xs, Ws, acc, jg, ng);
    #pragma unroll
    for (int r=0;r<4;r++){
      float bb = bih[c*128 + jg*4+r];
      #pragma unroll
      for (int cc=0;cc<4;cc++)
        giall[(size_t)(n0 + ng*4+cc)*384 + c*128 + jg*4 + r] = acc[r][cc] + bb;
    }
  }
}

// ---------------- Kernel 2: sequential decode ----------------
// 32 blocks x 512 threads; 255 steps; FOUR barriers/step (was 6):
//  - B3b killed: score lanes compute rn/eq inline from q_s[PAD16]+red2.
//  - Bs2+tail killed: every wave redundantly reduces all 256 cols (float4
//    spartS reads, in-lane first-max, dpp max + ballot + readlane) -> every
//    lane knows argmax/softmax-sum without a barrier. Argmax inputs keep the
//    R12 summation order -> tours bit-identical; lp differs at ulp level.
//  - One-off jobs spread across waves (keys-swap: w2-3, tours: t==384,
//    map-update: t==448, lp: t==320) to cut barrier skew on wave 0.

__global__ __launch_bounds__(512, 2) void decode_kernel(
    const float* __restrict__ emb,
    const float* __restrict__ keysE, const float* __restrict__ giall,
    const float* __restrict__ Whh, const float* __restrict__ bhh,
    const float* __restrict__ Wq1, const float* __restrict__ bq1,
    const float* __restrict__ Wq2, const float* __restrict__ bq2,
    const float* __restrict__ v,   const float* __restrict__ Wh,
    const float* __restrict__ bh,  const int* __restrict__ start_nodes,
    float* __restrict__ tours_o, float* __restrict__ lp_o)
{
  __shared__ __align__(16) float keys_s[128*KSTRIDE];  // 132 KB, transposed E-keys
  __shared__ __align__(16) float h_s[2][160];          // staggered (H2A)
  __shared__ __align__(16) float qh_s[160];            // staggered (H2A)
  __shared__ __align__(16) float q_s[160];             // PAD16 (raw q), also gctx scratch
  __shared__ __align__(16) float v_sp[160];            // PAD16 layout, -2*v
  __shared__ __align__(16) float spartS[8*SSTR];       // score partials (+init scratch)
  __shared__ int col2node_s[256], node2col_s[256];
  __shared__ float red2[8];

  const int t = threadIdx.x;
  const int b = blockIdx.x;
  const int g  = t >> 2, s3 = t & 3;   // 128 groups x 4 lanes (matvec)
  const int w  = t >> 6, L  = t & 63;
  const int oct = L & 7, dgrp = L >> 3; // score: col-octet, dim-group

  // register weights: Whh rows g,128+g,256+g (chunk s3*32); Wq1/Wq2 row g
  float4 whh4[3][8], wq14[8], wq24[8];
  {
    const float4* w0  = (const float4*)(Whh + (size_t)(g      )*128 + s3*32);
    const float4* w1  = (const float4*)(Whh + (size_t)(128 + g)*128 + s3*32);
    const float4* w2  = (const float4*)(Whh + (size_t)(256 + g)*128 + s3*32);
    const float4* q1p = (const float4*)(Wq1 + (size_t)g*128 + s3*32);
    const float4* q2p = (const float4*)(Wq2 + (size_t)g*128 + s3*32);
    #pragma unroll
    for (int i=0;i<8;i++){
      whh4[0][i]=w0[i]; whh4[1][i]=w1[i]; whh4[2][i]=w2[i];
      wq14[i]=q1p[i];   wq24[i]=q2p[i];
    }
  }
  const float br = bhh[g], bz = bhh[128+g], bn = bhh[256+g];
  const float b1g = bq1[g], b2g = bq2[g];

  if (t<128) v_sp[PAD16(t)] = -2.f * v[t];
  if (t<256){ col2node_s[t] = t; node2col_s[t] = t; }
  { // stage transposed E-keys: coalesced per d-row
    #pragma unroll
    for (int m=0;m<16;m++){
      int idx = m*512 + t; int d = idx>>6, q = idx&63;
      *(float4*)(keys_s + d*KSTRIDE + q*4) =
        *(const float4*)(keysE + (size_t)d*TTOT + b*256 + q*4);
    }
  }
  { // graph-context partial sums (4 parts x 64 nodes)
    int d = t & 127, part = t >> 7;
    float a = 0.f;
    const float* base = emb + (size_t)(b*256 + part*64)*128 + d;
    for (int i=0;i<64;i++) a += base[(size_t)i*128];
    spartS[part*128+d] = a;
  }
  int cur = start_nodes[b];
  __syncthreads();
  if (t<128){
    float a = 0.f;
    #pragma unroll
    for (int p=0;p<4;p++) a += spartS[p*128+t];
    q_s[t] = a * (1.f/256.f);          // gctx temp (plain idx, init only)
  }
  __syncthreads();
  if (t<128){ // hidden0 = gctx@Wh.T + bh  (write staggered)
    float a = bh[t];
    const float* wr = Wh + (size_t)t*128;
    for (int k=0;k<128;k++) a += wr[k]*q_s[k];
    h_s[0][H2A(t)] = a;
  }
  { // sv = sum(v)
    float xv = (t<128) ? v[t] : 0.f;
    float tot = dpp_wave_sum(xv);
    if (L==0) red2[w] = tot;
  }
  __syncthreads();
  float sv = 0.f;
  #pragma unroll
  for (int i=0;i<8;i++) sv += red2[i];

  // gi prefetch for step 0
  float gir=0.f, giz=0.f, gin=0.f;
  if (s3==0){
    const float* gp = giall + (size_t)cur*384 + g;
    gir = gp[0]; giz = gp[128]; gin = gp[256];
  }

  for (int step=0; step<255; step++){
    const int par = step & 1;
    const int V   = 255 - step;          // valid count after removing cur
    const int curl = cur - b*256;

    // ---- swap-remove cur's keys column (waves 2-3; reads PRE-update map) ----
    if (t >= 128 && t < 256){
      int r = t - 128;
      int px = node2col_s[curl];
      keys_s[r*KSTRIDE + px] = keys_s[r*KSTRIDE + V];
    }
    if (t == 384) tours_o[b*256+step] = (float)cur;   // wave 6

    // ---- phase A: gh dots + fused GRU -> h_s[par^1] ----
    {
      float a0=0.f,a1=0.f,a2=0.f;
      const float4* hc4 = (const float4*)(h_s[par] + s3*40);
      #pragma unroll
      for (int i=0;i<8;i++){
        float4 hv = hc4[i];
        a0 += dot4(whh4[0][i], hv);
        a1 += dot4(whh4[1][i], hv);
        a2 += dot4(whh4[2][i], hv);
      }
      a0 = quad_sum_dpp(a0);
      a1 = quad_sum_dpp(a1);
      a2 = quad_sum_dpp(a2);
      if (s3==0){
        float r = sigfast(gir + a0 + br);
        float z = sigfast(giz + a1 + bz);
        float n = tanhfast(gin + r*(a2 + bn));
        h_s[par^1][H2A(g)] = (1.f-z)*n + z*h_s[par][H2A(g)];
      }
    }
    __syncthreads();                                   // B1

    // ---- deferred index-map update (wave 7; race-free: all prev-step
    //      combine reads of col2node_s completed before B1) ----
    if (t == 448){
      int px = node2col_s[curl];
      int ln = col2node_s[V];
      col2node_s[px] = ln;
      node2col_s[ln] = px;
    }

    { // qh = relu(h@Wq1.T + bq1)
      float a=0.f;
      const float4* hc4 = (const float4*)(h_s[par^1] + s3*40);
      #pragma unroll
      for (int i=0;i<8;i++) a += dot4(wq14[i], hc4[i]);
      a = quad_sum_dpp(a);
      if (s3==0) qh_s[H2A(g)] = fmaxf(a + b1g, 0.f);
    }
    __syncthreads();                                   // B2

    { // q_raw = qh@Wq2.T + bq2 (PAD16 store) ; per-wave ssq via DPP
      float a=0.f;
      const float4* qc4 = (const float4*)(qh_s + s3*40);
      #pragma unroll
      for (int i=0;i<8;i++) a += dot4(wq24[i], qc4[i]);
      a = quad_sum_dpp(a);
      float qval = a + b2g;
      if (s3==0) q_s[PAD16(g)] = qval;
      float ssp = (s3==0) ? qval*qval : 0.f;
      float tot = dpp_wave_sum(ssp);
      if (L==0) red2[w] = tot;
    }
    __syncthreads();                                   // B3

    // ---- score: wave w -> cols 32w..32w+31 (whole-wave skip when 32w >= V);
    //      rn/eq computed inline (B3b eliminated) ----
    if (32*w < V){
      float ss = 0.f;
      #pragma unroll
      for (int i=0;i<8;i++) ss += red2[i];
      float rn = 1.f / fmaxf(sqrtf(ss), 1e-12f);
      const float* kbase = keys_s + dgrp*16*KSTRIDE + 32*w + oct*4;
      const float* qb    = q_s  + dgrp*20;
      const float* vbase = v_sp + dgrp*20;
      float4 acc = {0.f,0.f,0.f,0.f};
      #pragma unroll
      for (int jj=0;jj<16;jj++){
        float eqj = __builtin_amdgcn_exp2f(qb[jj] * rn * LOG2E2);
        float vj  = vbase[jj];
        float4 K = *(const float4*)(kbase + jj*KSTRIDE);
        float r0 = __builtin_amdgcn_rcpf(fmaf(K.x, eqj, 1.f));
        float r1 = __builtin_amdgcn_rcpf(fmaf(K.y, eqj, 1.f));
        float r2 = __builtin_amdgcn_rcpf(fmaf(K.z, eqj, 1.f));
        float r3 = __builtin_amdgcn_rcpf(fmaf(K.w, eqj, 1.f));
        acc.x = fmaf(vj, r0, acc.x);
        acc.y = fmaf(vj, r1, acc.y);
        acc.z = fmaf(vj, r2, acc.z);
        acc.w = fmaf(vj, r3, acc.w);
      }
      *(float4*)(spartS + dgrp*SSTR + 32*w + oct*4) = acc;
    }
    __syncthreads();                                   // Bs1

    // ---- redundant combine: EVERY wave reduces all 256 cols; every lane
    //      learns argmax + softmax sum -> no Bs2, no tail round-trip ----
    {
      const float* sp = spartS + 4*L;
      float sx=0.f, sy=0.f, sz=0.f, sw=0.f;
      #pragma unroll
      for (int i=0;i<8;i++){
        float4 p = *(const float4*)(sp + i*SSTR);
        sx += p.x; sy += p.y; sz += p.z; sw += p.w;
      }
      int c0 = 4*L;
      float vx = (c0+0 < V) ? sv+sx : -INFINITY;
      float vy = (c0+1 < V) ? sv+sy : -INFINITY;
      float vz = (c0+2 < V) ? sv+sz : -INFINITY;
      float vw = (c0+3 < V) ? sv+sw : -INFINITY;
      float bm = vx; int bc = c0;                 // first-max tie-break
      if (vy > bm){ bm=vy; bc=c0+1; }
      if (vz > bm){ bm=vz; bc=c0+2; }
      if (vw > bm){ bm=vw; bc=c0+3; }
      float m = dpp_wave_max(bm);
      unsigned long long mk = __ballot(bm == m);
      int flane = __ffsll(mk) - 1;                // lowest lane = lowest col
      int besti = __builtin_amdgcn_readlane(bc, flane);
      float es = __builtin_amdgcn_exp2f((vx-m)*LOG2E) + __builtin_amdgcn_exp2f((vy-m)*LOG2E)
               + __builtin_amdgcn_exp2f((vz-m)*LOG2E) + __builtin_amdgcn_exp2f((vw-m)*LOG2E);
      float S = dpp_wave_sum(es);
      cur = b*256 + col2node_s[besti];            // read pre-next-update map
      if (s3==0){   // prefetch next gi (consumed in next phase A)
        const float* gp = giall + (size_t)cur*384 + g;
        gir = gp[0]; giz = gp[128]; gin = gp[256];
      }
      if (t==320) lp_o[b*255+step] = logf(1.f/S + 1e-10f);  // wave 5
    }
    // no barrier: next step's keys-swap/phase-A touch no combine-read state
  }
  if (t==0) tours_o[b*256+255] = (float)cur;

  (void)oct;
}

extern "C" void kernel_launch(void* const* d_in, const int* in_sizes, int n_in,
                              void* d_out, int out_size, void* d_ws, size_t ws_size,
                              hipStream_t stream) {
  const float* emb  = (const float*)d_in[0];
  const int*   startn = (const int*)d_in[1];
  const float* Wq1 = (const float*)d_in[3];  const float* bq1 = (const float*)d_in[4];
  const float* Wq2 = (const float*)d_in[5];  const float* bq2 = (const float*)d_in[6];
  const float* Wk1 = (const float*)d_in[7];  const float* bk1 = (const float*)d_in[8];
  const float* Wk2 = (const float*)d_in[9];  const float* bk2 = (const float*)d_in[10];
  const float* Wih = (const float*)d_in[11]; const float* Whh = (const float*)d_in[12];
  const float* bih = (const float*)d_in[13]; const float* bhh = (const float*)d_in[14];
  const float* v   = (const float*)d_in[15]; const float* Wh  = (const float*)d_in[16];
  const float* bh  = (const float*)d_in[17];

  float* keysE = (float*)d_ws;               // exp(2*keys) TRANSPOSED [128][8192]
  float* giall = keysE + (size_t)TTOT*DD;    // [8192*384]

  float* outp = (float*)d_out;   // tours [32*256] then log_probs [32*255]

  precompute_kernel<<<256, 256, 0, stream>>>(emb, Wk1, bk1, Wk2, bk2, Wih, bih, keysE, giall);
  decode_kernel<<<NGR, 512, 0, stream>>>(emb, keysE, giall, Whh, bhh, Wq1, bq1, Wq2, bq2,
                                         v, Wh, bh, startn, outp, outp + TTOT);
}